// Round 11
// baseline (363.313 us; speedup 1.0000x reference)
//
#include <hip/hip_runtime.h>
#include <hip/hip_fp16.h>
#include <math.h>

#define NN 65536
#define TWO_PI 6.283185307179586f
#define HRSTR 264          // LDS row stride in half2 slots (264 % 32 == 8)
#define SWZ(m) ((m) ^ (((m) >> 4) & 15))
#define SWZI(m, r) (SWZ(m) ^ ((r) & 12))
#define CTOT 10829824ul

__constant__ int CLO[8]  = {-32768, -15360, -5376, -8192, -8192, -2048, -2048, -2048};
__constant__ int CWW[8]  = {65536, 42240, 16384, 16384, 16384, 4096, 4096, 4096};
__constant__ int CRING[8] = {0, 0, 1, 1, 1, 1, 1, 1};
__constant__ unsigned long COFF[8] = {0ul, 4194304ul, 6897664ul, 7946240ul,
                                      8994816ul, 10043392ul, 10305536ul, 10567680ul};

__device__ __forceinline__ void lds_fence() {
    asm volatile("s_waitcnt lgkmcnt(0)" ::: "memory");
}
__device__ __forceinline__ int rev16(int p) { return ((p & 3) << 2) | (p >> 2); }
__device__ __forceinline__ int rev64(int p) { return ((p & 3) << 4) | (p & 12) | (p >> 4); }
__device__ __forceinline__ float2 h2f(__half2 h) { return __half22float2(h); }
__device__ __forceinline__ __half2 f2h(float a, float b) {
    return __floats2half2_rn(a, b);
}

__device__ __forceinline__ int quarter_mask(int klo, int khi)
{
    int qm = 0;
#pragma unroll
    for (int qq = 0; qq < 4; ++qq) {
        int lo_q = 16384 * qq - 255;
        int hi_q = 16384 * qq + 16639;
        bool act;
        if (klo >= 0) act = (hi_q >= klo) && (lo_q <= khi);
        else          act = (lo_q <= khi) || (hi_q >= klo + NN);
        if (act) qm |= (1 << qq);
    }
    return qm;
}

__device__ __forceinline__ void build_tw6(float* twt, int t)
{
    if (t < 16) {
        float s1, c1; __sincosf((TWO_PI / 64.0f) * (float)t, &s1, &c1);
        float c2 = c1 * c1 - s1 * s1, s2 = 2.f * c1 * s1;
        float c3 = c2 * c1 - s2 * s1, s3 = c2 * s1 + s2 * c1;
        float* e = twt + 6 * t;
        e[0] = c1; e[1] = s1; e[2] = c2; e[3] = s2; e[4] = c3; e[5] = s3;
    }
}

template<int SIGN>
__device__ __forceinline__ void fft16(float* xr, float* xi, float* yr, float* yi)
{
    const float S = (SIGN > 0) ? 1.0f : -1.0f;
    const float C8 = 0.92387953251f, S8 = 0.38268343236f, R2 = 0.70710678119f;
#pragma unroll
    for (int n0 = 0; n0 < 4; ++n0) {
        float z0r=xr[n0],    z0i=xi[n0];
        float z1r=xr[n0+4],  z1i=xi[n0+4];
        float z2r=xr[n0+8],  z2i=xi[n0+8];
        float z3r=xr[n0+12], z3i=xi[n0+12];
        float t0r=z0r+z2r, t0i=z0i+z2i;
        float t1r=z0r-z2r, t1i=z0i-z2i;
        float t2r=z1r+z3r, t2i=z1i+z3i;
        float t3r=S*(z1r-z3r), t3i=S*(z1i-z3i);
        xr[n0]=t0r+t2r;      xi[n0]=t0i+t2i;
        xr[n0+4]=t1r-t3i;    xi[n0+4]=t1i+t3r;
        xr[n0+8]=t0r-t2r;    xi[n0+8]=t0i-t2i;
        xr[n0+12]=t1r+t3i;   xi[n0+12]=t1i-t3r;
    }
    {
        const float W1r=C8,  W1i=S*S8;
        const float W2r=R2,  W2i=S*R2;
        const float W3r=S8,  W3i=S*C8;
        const float W6r=-R2, W6i=S*R2;
        const float W9r=-C8, W9i=-S*S8;
#define TWID(idx, wr, wi) { float ar=xr[idx], ai=xi[idx]; xr[idx]=ar*(wr)-ai*(wi); xi[idx]=ar*(wi)+ai*(wr); }
        TWID(5,W1r,W1i)  TWID(9,W2r,W2i)   TWID(13,W3r,W3i)
        TWID(6,W2r,W2i)  { float ar=xr[10], ai=xi[10]; xr[10]=-S*ai; xi[10]=S*ar; } TWID(14,W6r,W6i)
        TWID(7,W3r,W3i)  TWID(11,W6r,W6i)  TWID(15,W9r,W9i)
#undef TWID
    }
#pragma unroll
    for (int p = 0; p < 4; ++p) {
        float z0r=xr[4*p],   z0i=xi[4*p];
        float z1r=xr[4*p+1], z1i=xi[4*p+1];
        float z2r=xr[4*p+2], z2i=xi[4*p+2];
        float z3r=xr[4*p+3], z3i=xi[4*p+3];
        float t0r=z0r+z2r, t0i=z0i+z2i;
        float t1r=z0r-z2r, t1i=z0i-z2i;
        float t2r=z1r+z3r, t2i=z1i+z3i;
        float t3r=S*(z1r-z3r), t3i=S*(z1i-z3i);
        yr[p]=t0r+t2r;     yi[p]=t0i+t2i;
        yr[p+4]=t1r-t3i;   yi[p+4]=t1i+t3r;
        yr[p+8]=t0r-t2r;   yi[p+8]=t0i-t2i;
        yr[p+12]=t1r+t3i;  yi[p+12]=t1i-t3r;
    }
}

// -------- packed-half2 256-pt FFT on one group's LDS row (16 lanes, one wave) --------
// OUT 0: complex (packed, SWZ). OUT 1: (|.|*mscale, 0) packed (SWZ).
// OUT 2: |.|*mscale as FLOAT, linear with halo pads (overwrites row; safe post-read).
template<int SIGN, bool BIGTW, int OUT, int PADL, int PADR>
__device__ __forceinline__ void fft256_pk(__half2* row, int u, int n1,
                                          float twrate, float mscale, int cxor, int qmask)
{
    float xr[16], xi[16], yr[16], yi[16];
#pragma unroll
    for (int qq = 0; qq < 4; ++qq) {
        if (qmask & (1 << qq)) {
#pragma unroll
            for (int j = 0; j < 4; ++j) {
                int b = qq * 4 + j;
                float2 v = h2f(row[SWZ(u + (b << 4)) ^ cxor]);
                xr[b] = v.x; xi[b] = v.y;
            }
        } else {
#pragma unroll
            for (int j = 0; j < 4; ++j) { xr[qq * 4 + j] = 0.f; xi[qq * 4 + j] = 0.f; }
        }
    }
    fft16<SIGN>(xr, xi, yr, yi);
    float sa, ca;
    __sincosf((float)SIGN * (TWO_PI / 256.0f) * (float)u, &sa, &ca);
    float twr = 1.f, twi = 0.f;
#pragma unroll
    for (int c = 0; c < 16; ++c) {
        row[SWZ((c << 4) + u) ^ cxor] = f2h(yr[c] * twr - yi[c] * twi,
                                            yr[c] * twi + yi[c] * twr);
        float nr = twr * ca - twi * sa; twi = twr * sa + twi * ca; twr = nr;
    }
    lds_fence();
#pragma unroll
    for (int a = 0; a < 16; ++a) {
        float2 v = h2f(row[SWZ((u << 4) + a) ^ cxor]);
        xr[a] = v.x; xi[a] = v.y;
    }
    fft16<SIGN>(xr, xi, yr, yi);
    float tbr = 1.f, tbi = 0.f, str = 1.f, sti = 0.f;
    if (BIGTW) {
        float s0, c0, s1, c1;
        __sincosf((float)SIGN * twrate * (float)(n1 * u), &s0, &c0);
        __sincosf((float)SIGN * twrate * (float)(n1 << 4), &s1, &c1);
        tbr = c0; tbi = s0; str = c1; sti = s1;
    }
#pragma unroll
    for (int d = 0; d < 16; ++d) {
        float vr = yr[d], vi = yi[d];
        if (BIGTW) {
            float pr = vr * tbr - vi * tbi, pi = vr * tbi + vi * tbr;
            vr = pr; vi = pi;
            float nr = tbr * str - tbi * sti; tbi = tbr * sti + tbi * str; tbr = nr;
        }
        int k = u + (d << 4);
        if (OUT == 1) {
            row[SWZ(k) ^ cxor] = f2h(sqrtf(fmaf(vr, vr, vi * vi)) * mscale, 0.f);
        } else if (OUT == 2) {
            float mag = sqrtf(fmaf(vr, vr, vi * vi)) * mscale;
            float* rf = (float*)row;
            rf[PADL + k] = mag;
            if (k >= 256 - PADL) rf[k - (256 - PADL)] = mag;
            if (k < PADR) rf[PADL + 256 + k] = mag;
        } else {
            row[SWZ(k) ^ cxor] = f2h(vr, vi);
        }
    }
    lds_fence();
}

// ---------- packed LDS radix-4 passes over the row axis ----------
template<int L, int CLOG, int RST, int SIGN, bool SWZC>
__device__ __forceinline__ void lds_dit_pk(__half2* pl, const float* twt, int t, int T)
{
    const float S = (float)SIGN;
    const int NC = 1 << CLOG;
    const int nbf = NC * (L >> 2);
    for (int h = 1; h < L; h <<= 2) {
        __syncthreads();
        for (int i = t; i < nbf; i += T) {
            int c = i & (NC - 1);
            int bf = i >> CLOG;
            int j = bf & (h - 1);
            int q0 = ((bf - j) << 2) + j;
            int r0 = q0, r1 = q0 + h, r2 = q0 + 2 * h, r3 = q0 + 3 * h;
            int a0, a1, a2, a3;
            if (SWZC) {
                a0 = r0 * RST + SWZI(c, r0); a1 = r1 * RST + SWZI(c, r1);
                a2 = r2 * RST + SWZI(c, r2); a3 = r3 * RST + SWZI(c, r3);
            } else {
                a0 = r0 * RST + c; a1 = r1 * RST + c; a2 = r2 * RST + c; a3 = r3 * RST + c;
            }
            float2 z0 = h2f(pl[a0]), z1 = h2f(pl[a1]);
            float2 z2 = h2f(pl[a2]), z3 = h2f(pl[a3]);
            float x0r=z0.x, x0i=z0.y, x1r=z1.x, x1i=z1.y;
            float x2r=z2.x, x2i=z2.y, x3r=z3.x, x3i=z3.y;
            if (h > 1) {
                const float* e = twt + 6 * (j * (16 / h));
                float cj = e[0], sj = S * e[1];
                float c2 = e[2], s2 = S * e[3];
                float c3 = e[4], s3 = S * e[5];
                float r;
                r = x1r * cj - x1i * sj; x1i = x1r * sj + x1i * cj; x1r = r;
                r = x2r * c2 - x2i * s2; x2i = x2r * s2 + x2i * c2; x2r = r;
                r = x3r * c3 - x3i * s3; x3i = x3r * s3 + x3i * c3; x3r = r;
            }
            float t0r = x0r + x2r, t0i = x0i + x2i;
            float t1r = x0r - x2r, t1i = x0i - x2i;
            float t2r = x1r + x3r, t2i = x1i + x3i;
            float t3r = -S * (x1i - x3i), t3i = S * (x1r - x3r);
            pl[a0] = f2h(t0r + t2r, t0i + t2i);
            pl[a1] = f2h(t1r + t3r, t1i + t3i);
            pl[a2] = f2h(t0r - t2r, t0i - t2i);
            pl[a3] = f2h(t1r - t3r, t1i - t3i);
        }
    }
    __syncthreads();
}

template<int L, int CLOG, int RST, int SIGN, bool SWZC>
__device__ __forceinline__ void lds_dif_pk(__half2* pl, const float* twt, int t, int T)
{
    const float S = (float)SIGN;
    const int NC = 1 << CLOG;
    const int nbf = NC * (L >> 2);
    for (int h = L >> 2; h >= 1; h >>= 2) {
        __syncthreads();
        for (int i = t; i < nbf; i += T) {
            int c = i & (NC - 1);
            int bf = i >> CLOG;
            int j = bf & (h - 1);
            int q0 = ((bf - j) << 2) + j;
            int r0 = q0, r1 = q0 + h, r2 = q0 + 2 * h, r3 = q0 + 3 * h;
            int a0, a1, a2, a3;
            if (SWZC) {
                a0 = r0 * RST + SWZI(c, r0); a1 = r1 * RST + SWZI(c, r1);
                a2 = r2 * RST + SWZI(c, r2); a3 = r3 * RST + SWZI(c, r3);
            } else {
                a0 = r0 * RST + c; a1 = r1 * RST + c; a2 = r2 * RST + c; a3 = r3 * RST + c;
            }
            float2 z0 = h2f(pl[a0]), z1 = h2f(pl[a1]);
            float2 z2 = h2f(pl[a2]), z3 = h2f(pl[a3]);
            float x0r=z0.x, x0i=z0.y, x1r=z1.x, x1i=z1.y;
            float x2r=z2.x, x2i=z2.y, x3r=z3.x, x3i=z3.y;
            float t0r = x0r + x2r, t0i = x0i + x2i;
            float t1r = x0r - x2r, t1i = x0i - x2i;
            float t2r = x1r + x3r, t2i = x1i + x3i;
            float t3r = -S * (x1i - x3i), t3i = S * (x1r - x3r);
            float y1r = t1r + t3r, y1i = t1i + t3i;
            float y2r = t0r - t2r, y2i = t0i - t2i;
            float y3r = t1r - t3r, y3i = t1i - t3i;
            pl[a0] = f2h(t0r + t2r, t0i + t2i);
            if (h > 1) {
                const float* e = twt + 6 * (j * (16 / h));
                float cj = e[0], sj = S * e[1];
                float c2 = e[2], s2 = S * e[3];
                float c3 = e[4], s3 = S * e[5];
                pl[a1] = f2h(y1r * cj - y1i * sj, y1r * sj + y1i * cj);
                pl[a2] = f2h(y2r * c2 - y2i * s2, y2r * s2 + y2i * c2);
                pl[a3] = f2h(y3r * c3 - y3i * s3, y3r * s3 + y3i * c3);
            } else {
                pl[a1] = f2h(y1r, y1i);
                pl[a2] = f2h(y2r, y2i);
                pl[a3] = f2h(y3r, y3i);
            }
        }
    }
    __syncthreads();
}

// fp32 fft256 for the XF chain (8 rows, fp32 precision kept)
template<int SIGN, bool BIGTW>
__device__ __forceinline__ void fft256_f32(float* rr, float* ri, int u, int n1,
                                           float twrate, int cxor)
{
    float xr[16], xi[16], yr[16], yi[16];
#pragma unroll
    for (int b = 0; b < 16; ++b) {
        int s = SWZ(u + (b << 4)) ^ cxor;
        xr[b] = rr[s]; xi[b] = ri[s];
    }
    fft16<SIGN>(xr, xi, yr, yi);
    float sa, ca;
    __sincosf((float)SIGN * (TWO_PI / 256.0f) * (float)u, &sa, &ca);
    float twr = 1.f, twi = 0.f;
#pragma unroll
    for (int c = 0; c < 16; ++c) {
        int s = SWZ((c << 4) + u) ^ cxor;
        rr[s] = yr[c] * twr - yi[c] * twi;
        ri[s] = yr[c] * twi + yi[c] * twr;
        float nr = twr * ca - twi * sa; twi = twr * sa + twi * ca; twr = nr;
    }
    lds_fence();
#pragma unroll
    for (int a = 0; a < 16; ++a) {
        int s = SWZ((u << 4) + a) ^ cxor;
        xr[a] = rr[s]; xi[a] = ri[s];
    }
    fft16<SIGN>(xr, xi, yr, yi);
    float tbr = 1.f, tbi = 0.f, str = 1.f, sti = 0.f;
    if (BIGTW) {
        float s0, c0, s1, c1;
        __sincosf((float)SIGN * twrate * (float)(n1 * u), &s0, &c0);
        __sincosf((float)SIGN * twrate * (float)(n1 << 4), &s1, &c1);
        tbr = c0; tbi = s0; str = c1; sti = s1;
    }
#pragma unroll
    for (int d = 0; d < 16; ++d) {
        float vr = yr[d], vi = yi[d];
        if (BIGTW) {
            float pr = vr * tbr - vi * tbi, pi = vr * tbi + vi * tbr;
            vr = pr; vi = pi;
            float nr = tbr * str - tbi * sti; tbi = tbr * sti + tbi * str; tbr = nr;
        }
        int s = SWZ(u + (d << 4)) ^ cxor;
        rr[s] = vr; ri[s] = vi;
    }
    lds_fence();
}

// ================= XF chain (fp32) + zero init fused =================
__global__ __launch_bounds__(256)
void xfz_kernel(const float* __restrict__ x, float2* __restrict__ D,
                float* __restrict__ outImag, int nz, float* __restrict__ S2acc, int na)
{
    __shared__ float sre[16 * HRSTR];
    __shared__ float sim[16 * HRSTR];
    const int t = threadIdx.x;
    const int blk = blockIdx.x;
    if (blk >= 128) {
        int i = (blk - 128) * 256 + t;
        if (i < nz) outImag[i] = 0.f;
        else if (i < nz + na) S2acc[i - nz] = 0.f;
        return;
    }
    const int r = blk >> 4;
    const int n10 = (blk & 15) << 4;
#pragma unroll
    for (int it = 0; it < 16; ++it) {
        int flat = it * 256 + t;
        int i = flat & 15, n2 = flat >> 4;
        int n = (n10 + i) + (n2 << 8);
        sre[i * HRSTR + SWZI(n2, i)] = x[(size_t)r * NN + n];
        sim[i * HRSTR + SWZI(n2, i)] = 0.f;
    }
    __syncthreads();
    const int g = t >> 4, u = t & 15;
    fft256_f32<-1, true>(sre + g * HRSTR, sim + g * HRSTR, u, n10 + g,
                         TWO_PI / (float)NN, g & 12);
    __syncthreads();
#pragma unroll
    for (int it = 0; it < 16; ++it) {
        int flat = it * 256 + t;
        int i = flat & 15, k2 = flat >> 4;
        int s = i * HRSTR + SWZI(k2, i);
        D[(size_t)r * NN + (k2 << 8) + (n10 + i)] = make_float2(sre[s], sim[s]);
    }
}

__global__ __launch_bounds__(256)
void xf_stage2(const float2* __restrict__ D, float2* __restrict__ XF)
{
    __shared__ float sre[16 * HRSTR];
    __shared__ float sim[16 * HRSTR];
    const int t = threadIdx.x;
    const int r = blockIdx.x >> 4;
    const int k20 = (blockIdx.x & 15) << 4;
#pragma unroll
    for (int it = 0; it < 16; ++it) {
        float2 v = D[(size_t)r * NN + ((size_t)(k20 + it) << 8) + t];
        sre[it * HRSTR + SWZI(t, it)] = v.x;
        sim[it * HRSTR + SWZI(t, it)] = v.y;
    }
    __syncthreads();
    const int g = t >> 4, u = t & 15;
    fft256_f32<-1, false>(sre + g * HRSTR, sim + g * HRSTR, u, 0, 0.f, g & 12);
    __syncthreads();
#pragma unroll
    for (int it = 0; it < 16; ++it) {
        int flat = it * 256 + t;
        int fi = flat & 15, k1 = flat >> 4;
        int s = fi * HRSTR + SWZI(k1, fi);
        XF[(size_t)r * NN + (size_t)(k20 + fi) + ((size_t)k1 << 8)] = make_float2(sre[s], sim[s]);
    }
}

// ===== shared-mem carve: sld (16*264 half2 = 16896B) | twt (384B) | wtab (512B) =====
#define SM_FLOATS 4480   // 17920 bytes

__device__ void d_fo_stage1(float* smf, int t, int blk, const float2* __restrict__ XF,
                            __half2* __restrict__ Dh)
{
    __half2* sld = (__half2*)smf;
    const int r = blk >> 4;
    const int n10 = (blk & 15) << 4;
    const int j1 = r >> 6, ql = r & 63;
    const int srow = ql >> 3, w = ql & 7;
    const int lam = j1 * 8 + w;
    const float xi = 0.35f * exp2f(-(float)lam * 0.125f);
    const float invsig = 8.0f / xi;
    const float kc = xi * (float)NN;
    const float Hh = 5.0f * (xi * 0.125f) * (float)NN;
    const int klo = (int)(kc - Hh), khi = (int)(kc + Hh) + 1;
    const int qm = (khi >= NN) ? 15 : quarter_mask(klo, khi);
#pragma unroll
    for (int it = 0; it < 16; ++it) {
        int i = t & 15, n2 = (it << 4) + (t >> 4);
        if (!(qm & (1 << (it >> 2)))) {
            sld[i * HRSTR + SWZI(n2, i)] = f2h(0.f, 0.f);
            continue;
        }
        int n = (n10 + i) + (n2 << 8);
        float nsf = (float)((n < NN / 2) ? n : n - NN);
        float vr = 0.f, vi = 0.f;
        if (fabsf(nsf - kc) <= Hh) {
            float2 v = XF[(size_t)srow * NN + n];
            float a = (nsf * (1.0f / (float)NN) - xi) * invsig;
            float wg = __expf(-0.5f * a * a) * 0.0625f;
            vr = v.x * wg; vi = v.y * wg;
        }
        sld[i * HRSTR + SWZI(n2, i)] = f2h(vr, vi);
    }
    __syncthreads();
    const int g = t >> 4, u = t & 15;
    fft256_pk<1, true, 0, 0, 0>(sld + g * HRSTR, u, n10 + g, TWO_PI / (float)NN, 1.f,
                                g & 12, qm);
    __syncthreads();
#pragma unroll
    for (int it = 0; it < 16; ++it) {
        int flat = it * 256 + t;
        int i = flat & 15, k2 = flat >> 4;
        Dh[(size_t)r * NN + (k2 << 8) + (n10 + i)] = sld[i * HRSTR + SWZI(k2, i)];
    }
}

__device__ void d_fo_mid(float* smf, int t, int blk, const __half2* __restrict__ Dh,
                         __half2* __restrict__ D2h)
{
    __half2* sld = (__half2*)smf;
    const int r = blk >> 4;
    const int k20 = (blk & 15) << 4;
#pragma unroll
    for (int it = 0; it < 16; ++it)
        sld[it * HRSTR + SWZI(t, it)] = Dh[(size_t)r * NN + ((size_t)(k20 + it) << 8) + t];
    __syncthreads();
    const int g = t >> 4, u = t & 15;
    __half2* row = sld + g * HRSTR;
    fft256_pk<1, false, 1, 0, 0>(row, u, 0, 0.f, 16.0f / (float)NN, g & 12, 15);
    fft256_pk<-1, true, 0, 0, 0>(row, u, k20 + g, TWO_PI / (float)NN, 1.f, g & 12, 15);
    __syncthreads();
#pragma unroll
    for (int it = 0; it < 16; ++it) {
        int flat = it * 256 + t;
        int i = flat & 15, k2 = flat >> 4;
        D2h[(size_t)r * NN + (k2 << 8) + (k20 + i)] = sld[i * HRSTR + SWZI(k2, i)];
    }
}

__device__ void d_fo_stage2(float* smf, int t, int blk, const __half2* __restrict__ D2h,
                            __half2* __restrict__ Cw)
{
    __half2* sld = (__half2*)smf;
    const int r = blk >> 4;
    const int k20 = (blk & 15) << 4;
    const int j1 = r >> 6, ql = r & 63;
#pragma unroll
    for (int it = 0; it < 16; ++it)
        sld[it * HRSTR + SWZI(t, it)] = D2h[(size_t)r * NN + ((size_t)(k20 + it) << 8) + t];
    __syncthreads();
    const int g = t >> 4, u = t & 15;
    fft256_pk<-1, false, 0, 0, 0>(sld + g * HRSTR, u, 0, 0.f, 1.f, g & 12, 15);
    __syncthreads();
    const size_t base = COFF[j1] + (size_t)ql * CWW[j1];
    const int lo = CLO[j1], Wd = CWW[j1];
#pragma unroll
    for (int it = 0; it < 16; ++it) {
        int flat = it * 256 + t;
        int fi = flat & 15, k1 = flat >> 4;
        int k = (k20 + fi) + (k1 << 8);
        int ksg = (k < NN / 2) ? k : k - NN;
        int idx = ksg - lo;
        if (idx >= 0 && idx < Wd)
            Cw[base + idx] = sld[fi * HRSTR + SWZI(k1, fi)];
    }
}

__device__ void d_sfold(float* smf, int t, int blk, const float2* __restrict__ XF,
                        const __half2* __restrict__ Cw, float* __restrict__ out)
{
    float* Gr = smf; float* Gi = smf + 256;
    const float invsigphi = 731.428571f;
    float ar = 0.f, ai = 0.f;
    if (blk < 8) {
#pragma unroll
        for (int qq = -4; qq <= 4; ++qq) {
            int ks = t + (qq << 8);
            int k = ks & (NN - 1);
            float a = ((float)ks * (1.0f / (float)NN)) * invsigphi;
            float wg = __expf(-0.5f * a * a);
            float2 v = XF[(size_t)blk * NN + k];
            ar = fmaf(v.x, wg, ar); ai = fmaf(v.y, wg, ai);
        }
    } else {
        int q = blk - 8;
        int j1 = q >> 6, ql = q & 63;
        size_t base = COFF[j1] + (size_t)ql * CWW[j1];
        int lo = CLO[j1], Wd = CWW[j1], ring = CRING[j1];
#pragma unroll
        for (int qq = -4; qq <= 4; ++qq) {
            int ks = t + (qq << 8);
            float a = ((float)ks * (1.0f / (float)NN)) * invsigphi;
            float wg = __expf(-0.5f * a * a);
            int idx = ring ? ((ks - lo) & (Wd - 1)) : (ks - lo);
            float2 v = h2f(Cw[base + idx]);
            ar = fmaf(v.x, wg, ar); ai = fmaf(v.y, wg, ai);
        }
    }
    Gr[t] = ar; Gi[t] = ai;
    __syncthreads();
    float sb, cb;
    __sincosf((TWO_PI / 256.0f) * (float)t, &sb, &cb);
    float wr = 1.f, wi = 0.f, s = 0.f;
    for (int kk = 0; kk < 256; ++kk) {
        s = fmaf(Gr[kk], wr, s);
        s = fmaf(-Gi[kk], wi, s);
        float nr = wr * cb - wi * sb; wi = wr * sb + wi * cb; wr = nr;
    }
    s *= (1.0f / (float)NN);
    float mag = sqrtf(fmaf(s, s, 1e-8f));
    float val = logf(mag + 1e-8f);
    int b, chan;
    if (blk < 8) { b = blk; chan = 0; }
    else { int q = blk - 8; int j1 = q >> 6, ql = q & 63; b = ql >> 3; chan = 1 + j1 * 8 + (ql & 7); }
    out[((size_t)b * 289 + chan) * 256 + t] = val;
}

__device__ __forceinline__ void so_decode_full(int q, int& j1, int& j2, int& rb)
{
    int pp = q >> 6;
    rb = q & 63;
    j2 = (pp == 0) ? 1 : 2;
    j1 = (pp == 0) ? 0 : pp - 1;
}
__device__ __forceinline__ void so_decode_dec16(int q, int& j1, int& j2, int& rb)
{
    int pp = q >> 6;
    rb = q & 63;
    j2 = (pp < 3) ? 3 : 4;
    j1 = (pp < 3) ? pp : pp - 3;
}

__device__ void d_so_stage1(float* smf, int t, int blk, const __half2* __restrict__ Cw,
                            __half2* __restrict__ Dh)
{
    __half2* sld = (__half2*)smf;
    const int r = blk >> 4;
    const int n10 = (blk & 15) << 4;
    int j1, j2, rb;
    so_decode_full(r, j1, j2, rb);
    const float xi2 = 0.35f * exp2f(-(float)j2);
    const float invsig = 1.0f / (0.6f * xi2);
    const float kc = xi2 * (float)NN;
    const float Hh = 5.0f * (0.6f * xi2) * (float)NN;
    const int klo = (int)(kc - Hh), khi = (int)(kc + Hh) + 1;
    const int qm = (klo >= 0 && khi >= NN) ? 15 : quarter_mask(klo, khi);
    const size_t base = COFF[j1] + (size_t)rb * CWW[j1];
    const int lo = CLO[j1], Wd = CWW[j1];
#pragma unroll
    for (int it = 0; it < 16; ++it) {
        int i = t & 15, n2 = (it << 4) + (t >> 4);
        if (!(qm & (1 << (it >> 2)))) {
            sld[i * HRSTR + SWZI(n2, i)] = f2h(0.f, 0.f);
            continue;
        }
        int n = (n10 + i) + (n2 << 8);
        int ksg = (n < NN / 2) ? n : n - NN;
        float nsf = (float)ksg;
        float vr = 0.f, vi = 0.f;
        int idx = ksg - lo;
        if (fabsf(nsf - kc) <= Hh && idx >= 0 && idx < Wd) {
            float2 v = h2f(Cw[base + idx]);
            float a = (nsf * (1.0f / (float)NN) - xi2) * invsig;
            float wg = __expf(-0.5f * a * a) * (1.0f / 256.0f);
            vr = v.x * wg; vi = v.y * wg;
        }
        sld[i * HRSTR + SWZI(n2, i)] = f2h(vr, vi);
    }
    __syncthreads();
    const int g = t >> 4, u = t & 15;
    fft256_pk<1, true, 0, 0, 0>(sld + g * HRSTR, u, n10 + g, TWO_PI / (float)NN, 1.f,
                                g & 12, qm);
    __syncthreads();
#pragma unroll
    for (int it = 0; it < 16; ++it) {
        int flat = it * 256 + t;
        int i = flat & 15, k2 = flat >> 4;
        Dh[(size_t)r * NN + (k2 << 8) + (n10 + i)] = sld[i * HRSTR + SWZI(k2, i)];
    }
}

__device__ void d_so_stage2(float* smf, int t, int blk, const __half2* __restrict__ Dh,
                            float* __restrict__ S2acc)
{
    __half2* sld = (__half2*)smf;
    float* wtab = smf + 4320;   // [16][8]
    const int r = blk >> 4;
    const int k20 = (blk & 15) << 4;
#pragma unroll
    for (int it = 0; it < 16; ++it)
        sld[it * HRSTR + SWZI(t, it)] = Dh[(size_t)r * NN + ((size_t)(k20 + it) << 8) + t];
    if (t < 128) {
        int fi = t >> 3, dd = (t & 7) - 4;
        int w = k20 + fi + (dd << 8) + 768;
        float val = 0.f;
        if (w >= 0 && w <= 1536) {
            float m = (float)(w - 768);
            val = 0.003426963f * __expf(-3.690276e-5f * m * m);
        }
        wtab[fi * 8 + (t & 7)] = val;
    }
    __syncthreads();
    const int g = t >> 4, u = t & 15;
    fft256_pk<1, false, 2, 4, 3>(sld + g * HRSTR, u, 0, 0.f, 1.f, g & 12, 15);
    __syncthreads();
    float acc = 0.f;
#pragma unroll
    for (int fi = 0; fi < 16; ++fi) {
        const float* row = (const float*)(sld + fi * HRSTR);
#pragma unroll
        for (int dd = 0; dd < 8; ++dd)
            acc = fmaf(row[t + dd], wtab[fi * 8 + dd], acc);
    }
    atomicAdd(&S2acc[(size_t)r * 256 + t], acc * (1.0f / 256.0f));
}

template<int MODE>
__device__ void d_dec16_s1(float* smf, int t, int blk, const float2* __restrict__ XF,
                           const __half2* __restrict__ Cw, __half2* __restrict__ Dh16)
{
    __half2* sld = (__half2*)smf;           // 64x64
    float* twt = smf + 4224;
    const int r = blk >> 2;
    const int c0 = (blk & 3) << 6;
    float xi, invsig, kc, Hh; int srow = 0; size_t cbase = 0; int lo = 0, Wd = 0, ring = 0;
    if (MODE == 1) {
        int j1 = 2 + (r >> 6); int ql = r & 63; srow = ql >> 3;
        int lam = j1 * 8 + (ql & 7);
        xi = 0.35f * exp2f(-(float)lam * 0.125f);
        invsig = 8.0f / xi; kc = xi * (float)NN; Hh = 6.10f * (xi * 0.125f) * (float)NN;
    } else {
        int j1, j2, rb;
        so_decode_dec16(r, j1, j2, rb);
        xi = 0.35f * exp2f(-(float)j2);
        invsig = 1.0f / (0.6f * xi); kc = xi * (float)NN;
        Hh = fminf(6.10f * (0.6f * xi) * (float)NN, 7967.0f);
        cbase = COFF[j1] + (size_t)rb * CWW[j1]; lo = CLO[j1]; Wd = CWW[j1]; ring = CRING[j1];
    }
    build_tw6(twt, t);
    const int klo = (int)ceilf(kc - Hh);
#pragma unroll
    for (int it = 0; it < 16; ++it) {
        int flat = it * 256 + t;
        int c = flat & 63, n2 = flat >> 6;
        int kap = (c0 + c) + (n2 << 8);
        int kk = klo + (int)(((unsigned)(kap - klo)) & 16383u);
        float vr = 0.f, vi = 0.f;
        if (fabsf((float)kk - kc) <= Hh) {
            float2 v;
            bool ok = true;
            if (MODE == 1) v = XF[(size_t)srow * NN + (kk & (NN - 1))];
            else {
                int idx;
                if (ring) idx = (kk - lo) & (Wd - 1);
                else { idx = kk - lo; ok = (idx >= 0 && idx < Wd); }
                v = ok ? h2f(Cw[cbase + idx]) : make_float2(0.f, 0.f);
            }
            float a = ((float)kk * (1.0f / (float)NN) - xi) * invsig;
            float wg = __expf(-0.5f * a * a) * 0.015625f;
            vr = v.x * wg; vi = v.y * wg;
        }
        int p = rev64(n2);
        sld[(p << 6) + c] = f2h(vr, vi);
    }
    lds_dit_pk<64, 6, 64, 1, false>(sld, twt, t, 256);
    {
        const int c = t & 63, r0 = t >> 6;
        float sA, cA, sD, cD;
        __sincosf((TWO_PI / 16384.0f) * (float)(r0 * (c0 + c)), &sA, &cA);
        __sincosf((TWO_PI / 16384.0f) * (float)(4 * (c0 + c)), &sD, &cD);
#pragma unroll
        for (int it = 0; it < 16; ++it) {
            int row = (it << 2) + r0;
            int a = (row << 6) + c;
            float2 z = h2f(sld[a]);
            sld[a] = f2h(z.x * cA - z.y * sA, z.x * sA + z.y * cA);
            float nc = cA * cD - sA * sD; sA = cA * sD + sA * cD; cA = nc;
        }
    }
    __syncthreads();
#pragma unroll
    for (int it = 0; it < 16; ++it) {
        int flat = it * 256 + t;
        int c = flat & 63, row = flat >> 6;
        Dh16[(size_t)r * 16384 + (row << 8) + (c0 + c)] = sld[(row << 6) + c];
    }
}

__device__ void d_dec16_s2so(float* smf, int t, int blk, const __half2* __restrict__ Dh16,
                             float* __restrict__ S2acc)
{
    __half2* sld = (__half2*)smf;
    float* wtab = smf + 4320;   // [16][6]
    const int r = blk >> 2;
    const int k2base = (blk & 3) << 4;
#pragma unroll
    for (int it = 0; it < 16; ++it)
        sld[it * HRSTR + SWZI(t, it)] = Dh16[(size_t)r * 16384 + ((k2base + it) << 8) + t];
    if (t < 96) {
        int p = t / 6, dl = t % 6;
        float w = (float)(256 * (dl - 2) - 4 * (k2base + p));
        wtab[p * 6 + dl] = 0.003426963f * __expf(-3.690276e-5f * w * w);
    }
    __syncthreads();
    const int g = t >> 4, u = t & 15;
    fft256_pk<1, false, 2, 3, 2>(sld + g * HRSTR, u, 0, 0.f, 64.0f / (float)NN, g & 12, 15);
    __syncthreads();
    float acc = 0.f;
#pragma unroll
    for (int p = 0; p < 16; ++p) {
        const float* row = (const float*)(sld + p * HRSTR);
#pragma unroll
        for (int dl = 0; dl < 6; ++dl)
            acc = fmaf(row[t + 5 - dl], wtab[p * 6 + dl], acc);
    }
    atomicAdd(&S2acc[(size_t)(192 + r) * 256 + t], acc * 4.0f);
}

__device__ void d_dec16_s2fo(float* smf, int t, int blk, const __half2* __restrict__ Dh16,
                             __half2* __restrict__ D2h16)
{
    __half2* sld = (__half2*)smf;
    const int r = blk >> 2;
    const int k2base = (blk & 3) << 4;
#pragma unroll
    for (int it = 0; it < 16; ++it)
        sld[it * HRSTR + SWZI(t, it)] = Dh16[(size_t)r * 16384 + ((k2base + it) << 8) + t];
    __syncthreads();
    const int g = t >> 4, u = t & 15;
    __half2* row = sld + g * HRSTR;
    fft256_pk<1, false, 1, 0, 0>(row, u, 0, 0.f, 256.0f / (float)NN, g & 12, 15);
    fft256_pk<-1, true, 0, 0, 0>(row, u, k2base + g, TWO_PI / 16384.0f, 1.f, g & 12, 15);
    __syncthreads();
#pragma unroll
    for (int it = 0; it < 16; ++it)
        D2h16[(size_t)r * 16384 + ((k2base + it) << 8) + t] = sld[it * HRSTR + SWZI(t, it)];
}

__device__ void d_dec16_s3fo(float* smf, int t, int blk, const __half2* __restrict__ D2h16,
                             __half2* __restrict__ Cw)
{
    __half2* sld = (__half2*)smf;
    float* twt = smf + 4224;
    const int r = blk >> 2;
    const int c0 = (blk & 3) << 6;
    const int j1 = 2 + (r >> 6), ql = r & 63;
    build_tw6(twt, t);
#pragma unroll
    for (int it = 0; it < 16; ++it) {
        int flat = it * 256 + t;
        int c = flat & 63, m2 = flat >> 6;
        sld[(m2 << 6) + c] = D2h16[(size_t)r * 16384 + (m2 << 8) + (c0 + c)];
    }
    lds_dif_pk<64, 6, 64, -1, false>(sld, twt, t, 256);
    const int lo = CLO[j1];
    const size_t rbase = COFF[j1] + (size_t)ql * 16384;
#pragma unroll
    for (int it = 0; it < 16; ++it) {
        int flat = it * 256 + t;
        int c = flat & 63, p = flat >> 6;
        int kap = (c0 + c) + (rev64(p) << 8);
        int ks = (kap < 8192) ? kap : kap - 16384;
        int idx = (ks - lo) & 16383;
        Cw[rbase + idx] = sld[(p << 6) + c];
    }
}

__device__ void d_m4k_fo(float* smf, int t, int blk, const float2* __restrict__ XF,
                         __half2* __restrict__ Cw)
{
    __half2* sld = (__half2*)smf;
    float* twt = smf + 4224;
    const int j1 = 5 + (blk >> 6), ql = blk & 63;
    const int srow = ql >> 3;
    const int lam = j1 * 8 + (ql & 7);
    const float xi = 0.35f * exp2f(-(float)lam * 0.125f);
    const float invsig = 8.0f / xi;
    const float kc = xi * (float)NN;
    const float Hh = 6.10f * (xi * 0.125f) * (float)NN;
    const int klo = (int)ceilf(kc - Hh);
    build_tw6(twt, t);
#pragma unroll
    for (int it = 0; it < 16; ++it) {
        int kap = t + (it << 8);
        int kk = klo + (int)(((unsigned)(kap - klo)) & 4095u);
        float vr = 0.f, vi = 0.f;
        if (fabsf((float)kk - kc) <= Hh) {
            float2 v = XF[(size_t)srow * NN + (kk & (NN - 1))];
            float a = ((float)kk * (1.0f / (float)NN) - xi) * invsig;
            float wg = __expf(-0.5f * a * a);
            vr = v.x * wg; vi = v.y * wg;
        }
        int p = rev16(it);
        sld[p * HRSTR + SWZI(t, p)] = f2h(vr, vi);
    }
    lds_dit_pk<16, 8, HRSTR, 1, true>(sld, twt, t, 256);
    {
        float sD, cD; __sincosf((TWO_PI / 4096.0f) * (float)t, &sD, &cD);
        float cA = 1.f, sA = 0.f;
#pragma unroll
        for (int it = 0; it < 16; ++it) {
            int a = it * HRSTR + SWZI(t, it);
            float2 z = h2f(sld[a]);
            sld[a] = f2h(z.x * cA - z.y * sA, z.x * sA + z.y * cA);
            float nc = cA * cD - sA * sD; sA = cA * sD + sA * cD; cA = nc;
        }
    }
    __syncthreads();
    const int g = t >> 4, u = t & 15;
    __half2* row = sld + g * HRSTR;
    fft256_pk<1, false, 1, 0, 0>(row, u, 0, 0.f, 16.0f / (float)NN, g & 12, 15);
    fft256_pk<-1, true, 0, 0, 0>(row, u, g, TWO_PI / 4096.0f, 1.f, g & 12, 15);
    lds_dif_pk<16, 8, HRSTR, -1, true>(sld, twt, t, 256);
    const int lo = CLO[j1];
    const size_t rbase = COFF[j1] + (size_t)ql * 4096;
#pragma unroll
    for (int it = 0; it < 16; ++it) {
        int kap = t + (rev16(it) << 8);
        int ks = (kap < 2048) ? kap : kap - 4096;
        int idx = (ks - lo) & 4095;
        Cw[rbase + idx] = sld[it * HRSTR + SWZI(t, it)];
    }
}

__device__ void d_m4k_so(float* smf, int t, int blk, const __half2* __restrict__ Cw,
                         float* __restrict__ out)
{
    __half2* sld = (__half2*)smf;
    float* twt = smf + 4224;
    float* wtab = smf + 4320;   // [16][6]
    const int pp = blk >> 6, rb = blk & 63;
    int j1, j2;
    if (pp < 5)       { j2 = 5; j1 = pp; }
    else if (pp < 11) { j2 = 6; j1 = pp - 5; }
    else              { j2 = 7; j1 = pp - 11; }
    const float xi2 = 0.35f * exp2f(-(float)j2);
    const float invsig = 1.0f / (0.6f * xi2);
    const float kc = xi2 * (float)NN;
    const float Hh = fminf(6.10f * (0.6f * xi2) * (float)NN, 1823.0f);
    const int klo = (int)ceilf(kc - Hh);
    const size_t cbase = COFF[j1] + (size_t)rb * CWW[j1];
    const int lo = CLO[j1], Wd = CWW[j1], ring = CRING[j1];
    build_tw6(twt, t);
#pragma unroll
    for (int it = 0; it < 16; ++it) {
        int kap = t + (it << 8);
        int kk = klo + (int)(((unsigned)(kap - klo)) & 4095u);
        float vr = 0.f, vi = 0.f;
        if (fabsf((float)kk - kc) <= Hh) {
            int idx; bool ok = true;
            if (ring) idx = (kk - lo) & (Wd - 1);
            else { idx = kk - lo; ok = (idx >= 0 && idx < Wd); }
            if (ok) {
                float2 v = h2f(Cw[cbase + idx]);
                float a = ((float)kk * (1.0f / (float)NN) - xi2) * invsig;
                float wg = __expf(-0.5f * a * a);
                vr = v.x * wg; vi = v.y * wg;
            }
        }
        int p = rev16(it);
        sld[p * HRSTR + SWZI(t, p)] = f2h(vr, vi);
    }
    if (t < 96) {
        int p = t / 6, dl = t % 6;
        float w = (float)(256 * (dl - 2) - 16 * p);
        wtab[p * 6 + dl] = 0.003426963f * __expf(-3.690276e-5f * w * w);
    }
    lds_dit_pk<16, 8, HRSTR, 1, true>(sld, twt, t, 256);
    {
        float sD, cD; __sincosf((TWO_PI / 4096.0f) * (float)t, &sD, &cD);
        float cA = 1.f, sA = 0.f;
#pragma unroll
        for (int it = 0; it < 16; ++it) {
            int a = it * HRSTR + SWZI(t, it);
            float2 z = h2f(sld[a]);
            sld[a] = f2h(z.x * cA - z.y * sA, z.x * sA + z.y * cA);
            float nc = cA * cD - sA * sD; sA = cA * sD + sA * cD; cA = nc;
        }
    }
    __syncthreads();
    const int g = t >> 4, u = t & 15;
    fft256_pk<1, false, 2, 3, 2>(sld + g * HRSTR, u, 0, 0.f, 1.0f / (float)NN, g & 12, 15);
    __syncthreads();
    float acc = 0.f;
#pragma unroll
    for (int p = 0; p < 16; ++p) {
        const float* row = (const float*)(sld + p * HRSTR);
#pragma unroll
        for (int dl = 0; dl < 6; ++dl)
            acc = fmaf(row[t + 5 - dl], wtab[p * 6 + dl], acc);
    }
    acc *= 16.0f;
    const int b = rb >> 3;
    const int chan = 65 + 4 * j2 * (j2 - 1) + j1 * 8 + (rb & 7);
    float mag = sqrtf(fmaf(acc, acc, 1e-8f));
    out[((size_t)b * 289 + chan) * 256 + t] = logf(mag + 1e-8f);
}

// ================= dispatchers =================
__global__ __launch_bounds__(256)
void fo_s1_kernel(const float2* __restrict__ XF, __half2* __restrict__ Cw,
                  __half2* __restrict__ DhB, __half2* __restrict__ Dh16)
{
    __shared__ float smf[SM_FLOATS];
    const int t = threadIdx.x;
    const int b = blockIdx.x;
    if (b < 192) d_m4k_fo(smf, t, b, XF, Cw);
    else if (b < 960) d_dec16_s1<1>(smf, t, b - 192, XF, nullptr, Dh16);
    else d_fo_stage1(smf, t, b - 960, XF, DhB);
}

__global__ __launch_bounds__(256)
void fo_s2_kernel(const __half2* __restrict__ DhB, const __half2* __restrict__ Dh16,
                  __half2* __restrict__ D2h, __half2* __restrict__ D2h16)
{
    __shared__ float smf[SM_FLOATS];
    const int t = threadIdx.x;
    const int b = blockIdx.x;
    if (b < 768) d_dec16_s2fo(smf, t, b, Dh16, D2h16);
    else d_fo_mid(smf, t, b - 768, DhB, D2h);
}

__global__ __launch_bounds__(256)
void fo_s3_kernel(const __half2* __restrict__ D2h, const __half2* __restrict__ D2h16,
                  __half2* __restrict__ Cw)
{
    __shared__ float smf[SM_FLOATS];
    const int t = threadIdx.x;
    const int b = blockIdx.x;
    if (b < 768) d_dec16_s3fo(smf, t, b, D2h16, Cw);
    else d_fo_stage2(smf, t, b - 768, D2h, Cw);
}

__global__ __launch_bounds__(256)
void so_1_kernel(const float2* __restrict__ XF, const __half2* __restrict__ Cw,
                 __half2* __restrict__ DhS, __half2* __restrict__ Dh16so,
                 float* __restrict__ out)
{
    __shared__ float smf[SM_FLOATS];
    const int t = threadIdx.x;
    const int b = blockIdx.x;
    if (b < 1152) d_m4k_so(smf, t, b, Cw, out);
    else if (b < 2944) d_dec16_s1<2>(smf, t, b - 1152, nullptr, Cw, Dh16so);
    else if (b < 6016) d_so_stage1(smf, t, b - 2944, Cw, DhS);
    else d_sfold(smf, t, b - 6016, XF, Cw, out);
}

__global__ __launch_bounds__(256)
void so_2_kernel(const __half2* __restrict__ DhS, const __half2* __restrict__ Dh16so,
                 float* __restrict__ S2acc)
{
    __shared__ float smf[SM_FLOATS];
    const int t = threadIdx.x;
    const int b = blockIdx.x;
    if (b < 1792) d_dec16_s2so(smf, t, b, Dh16so, S2acc);
    else d_so_stage2(smf, t, b - 1792, DhS, S2acc);
}

__global__ __launch_bounds__(256)
void s2final(const float* __restrict__ S2acc, float* __restrict__ out)
{
    const int q = blockIdx.x, n = threadIdx.x;
    int j1, j2, rb;
    if (q < 192) so_decode_full(q, j1, j2, rb);
    else         so_decode_dec16(q - 192, j1, j2, rb);
    const int b = rb >> 3;
    const int chan = 65 + 4 * j2 * (j2 - 1) + j1 * 8 + (rb & 7);
    float s = S2acc[(size_t)q * 256 + n];
    float mag = sqrtf(fmaf(s, s, 1e-8f));
    out[((size_t)b * 289 + chan) * 256 + n] = logf(mag + 1e-8f);
}

extern "C" void kernel_launch(void* const* d_in, const int* in_sizes, int n_in,
                              void* d_out, int out_size, void* d_ws, size_t ws_size,
                              hipStream_t stream)
{
    const float* x = (const float*)d_in[0];
    float* out = (float*)d_out;
    char* ws = (char*)d_ws;

    size_t off = 0;
    float2*  XF    = (float2*)ws;                 off += 8ul * NN * 8;
    __half2* Cw    = (__half2*)(ws + off);        off += CTOT * 4ul;
    float*   S2acc = (float*)(ws + off);          off += 640ul * 256 * 4;
    off = (off + 255) & ~255ul;
    char* sc = ws + off;

    __half2* DhB   = (__half2*)sc;                        // 32 MB
    __half2* D2h   = (__half2*)(sc + 33554432ul);         // 32 MB
    __half2* Dh16  = (__half2*)(sc + 67108864ul);         // 12 MB
    __half2* D2h16 = (__half2*)(sc + 79691776ul);         // 12 MB
    __half2* DhS    = (__half2*)sc;                       // 48 MB (so phase reuse)
    __half2* Dh16so = (__half2*)(sc + 50331648ul);        // 28 MB
    float2*  Df     = (float2*)sc;                        // 4 MB (XF scratch)

    const int nz = 8 * 289 * 256;
    const int na = 640 * 256;
    const int zb = (nz + na + 255) / 256;

    // XF stage1 + zero init fused; then XF stage2
    xfz_kernel<<<128 + zb, 256, 0, stream>>>(x, Df, out + nz, nz, S2acc, na);
    xf_stage2<<<8 * 16, 256, 0, stream>>>(Df, XF);

    // first order, all resolutions, stage-wise fused (packed-half2 LDS)
    fo_s1_kernel<<<3008, 256, 0, stream>>>(XF, Cw, DhB, Dh16);
    fo_s2_kernel<<<2816, 256, 0, stream>>>(DhB, Dh16, D2h, D2h16);
    fo_s3_kernel<<<2816, 256, 0, stream>>>(D2h, D2h16, Cw);

    // second order + S0/S1, fused
    so_1_kernel<<<6536, 256, 0, stream>>>(XF, Cw, DhS, Dh16so, out);
    so_2_kernel<<<4864, 256, 0, stream>>>(DhS, Dh16so, S2acc);
    s2final<<<640, 256, 0, stream>>>(S2acc, out);
}

// Round 12
// 257.325 us; speedup vs baseline: 1.4119x; 1.4119x over previous
//
#include <hip/hip_runtime.h>
#include <hip/hip_fp16.h>
#include <math.h>

#define NN 65536
#define TWO_PI 6.283185307179586f
#define RSTR 264
#define SWZ(m) ((m) ^ (((m) >> 4) & 15))
#define SWZI(m, r) (SWZ(m) ^ ((r) & 12))
#define CTOT 10829824ul

__constant__ int CLO[8]  = {-32768, -15360, -5376, -8192, -8192, -2048, -2048, -2048};
__constant__ int CWW[8]  = {65536, 42240, 16384, 16384, 16384, 4096, 4096, 4096};
__constant__ int CRING[8] = {0, 0, 1, 1, 1, 1, 1, 1};
__constant__ unsigned long COFF[8] = {0ul, 4194304ul, 6897664ul, 7946240ul,
                                      8994816ul, 10043392ul, 10305536ul, 10567680ul};

__device__ __forceinline__ void lds_fence() {
    asm volatile("s_waitcnt lgkmcnt(0)" ::: "memory");
}
__device__ __forceinline__ int rev16(int p) { return ((p & 3) << 2) | (p >> 2); }
__device__ __forceinline__ int rev64(int p) { return ((p & 3) << 4) | (p & 12) | (p >> 4); }

__device__ __forceinline__ int quarter_mask(int klo, int khi)
{
    int qm = 0;
#pragma unroll
    for (int qq = 0; qq < 4; ++qq) {
        int lo_q = 16384 * qq - 255;
        int hi_q = 16384 * qq + 16639;
        bool act;
        if (klo >= 0) act = (hi_q >= klo) && (lo_q <= khi);
        else          act = (lo_q <= khi) || (hi_q >= klo + NN);
        if (act) qm |= (1 << qq);
    }
    return qm;
}

__device__ __forceinline__ void build_tw6(float* twt, int t)
{
    if (t < 16) {
        float s1, c1; __sincosf((TWO_PI / 64.0f) * (float)t, &s1, &c1);
        float c2 = c1 * c1 - s1 * s1, s2 = 2.f * c1 * s1;
        float c3 = c2 * c1 - s2 * s1, s3 = c2 * s1 + s2 * c1;
        float* e = twt + 6 * t;
        e[0] = c1; e[1] = s1; e[2] = c2; e[3] = s2; e[4] = c3; e[5] = s3;
    }
}

template<int SIGN>
__device__ __forceinline__ void fft16(float* xr, float* xi, float* yr, float* yi)
{
    const float S = (SIGN > 0) ? 1.0f : -1.0f;
    const float C8 = 0.92387953251f, S8 = 0.38268343236f, R2 = 0.70710678119f;
#pragma unroll
    for (int n0 = 0; n0 < 4; ++n0) {
        float z0r=xr[n0],    z0i=xi[n0];
        float z1r=xr[n0+4],  z1i=xi[n0+4];
        float z2r=xr[n0+8],  z2i=xi[n0+8];
        float z3r=xr[n0+12], z3i=xi[n0+12];
        float t0r=z0r+z2r, t0i=z0i+z2i;
        float t1r=z0r-z2r, t1i=z0i-z2i;
        float t2r=z1r+z3r, t2i=z1i+z3i;
        float t3r=S*(z1r-z3r), t3i=S*(z1i-z3i);
        xr[n0]=t0r+t2r;      xi[n0]=t0i+t2i;
        xr[n0+4]=t1r-t3i;    xi[n0+4]=t1i+t3r;
        xr[n0+8]=t0r-t2r;    xi[n0+8]=t0i-t2i;
        xr[n0+12]=t1r+t3i;   xi[n0+12]=t1i-t3r;
    }
    {
        const float W1r=C8,  W1i=S*S8;
        const float W2r=R2,  W2i=S*R2;
        const float W3r=S8,  W3i=S*C8;
        const float W6r=-R2, W6i=S*R2;
        const float W9r=-C8, W9i=-S*S8;
#define TWID(idx, wr, wi) { float ar=xr[idx], ai=xi[idx]; xr[idx]=ar*(wr)-ai*(wi); xi[idx]=ar*(wi)+ai*(wr); }
        TWID(5,W1r,W1i)  TWID(9,W2r,W2i)   TWID(13,W3r,W3i)
        TWID(6,W2r,W2i)  { float ar=xr[10], ai=xi[10]; xr[10]=-S*ai; xi[10]=S*ar; } TWID(14,W6r,W6i)
        TWID(7,W3r,W3i)  TWID(11,W6r,W6i)  TWID(15,W9r,W9i)
#undef TWID
    }
#pragma unroll
    for (int p = 0; p < 4; ++p) {
        float z0r=xr[4*p],   z0i=xi[4*p];
        float z1r=xr[4*p+1], z1i=xi[4*p+1];
        float z2r=xr[4*p+2], z2i=xi[4*p+2];
        float z3r=xr[4*p+3], z3i=xi[4*p+3];
        float t0r=z0r+z2r, t0i=z0i+z2i;
        float t1r=z0r-z2r, t1i=z0i-z2i;
        float t2r=z1r+z3r, t2i=z1i+z3i;
        float t3r=S*(z1r-z3r), t3i=S*(z1i-z3i);
        yr[p]=t0r+t2r;     yi[p]=t0i+t2i;
        yr[p+4]=t1r-t3i;   yi[p+4]=t1i+t3r;
        yr[p+8]=t0r-t2r;   yi[p+8]=t0i-t2i;
        yr[p+12]=t1r+t3i;  yi[p+12]=t1i-t3r;
    }
}

template<int SIGN, bool BIGTW, int OUT, bool INREAL, int PADL, int PADR>
__device__ __forceinline__ void fft256_soa(float* rr, float* ri, int u, int n1,
                                           float twrate, float mscale, int cxor, int qmask)
{
    float xr[16], xi[16], yr[16], yi[16];
#pragma unroll
    for (int qq = 0; qq < 4; ++qq) {
        if (qmask & (1 << qq)) {
#pragma unroll
            for (int j = 0; j < 4; ++j) {
                int b = qq * 4 + j;
                int s = SWZ(u + (b << 4)) ^ cxor;
                xr[b] = rr[s];
                xi[b] = INREAL ? 0.f : ri[s];
            }
        } else {
#pragma unroll
            for (int j = 0; j < 4; ++j) { xr[qq * 4 + j] = 0.f; xi[qq * 4 + j] = 0.f; }
        }
    }
    fft16<SIGN>(xr, xi, yr, yi);
    float sa, ca;
    __sincosf((float)SIGN * (TWO_PI / 256.0f) * (float)u, &sa, &ca);
    float twr = 1.f, twi = 0.f;
#pragma unroll
    for (int c = 0; c < 16; ++c) {
        int s = SWZ((c << 4) + u) ^ cxor;
        rr[s] = yr[c] * twr - yi[c] * twi;
        ri[s] = yr[c] * twi + yi[c] * twr;
        float nr = twr * ca - twi * sa; twi = twr * sa + twi * ca; twr = nr;
    }
    lds_fence();
#pragma unroll
    for (int a = 0; a < 16; ++a) {
        int s = SWZ((u << 4) + a) ^ cxor;
        xr[a] = rr[s]; xi[a] = ri[s];
    }
    fft16<SIGN>(xr, xi, yr, yi);
    float tbr = 1.f, tbi = 0.f, str = 1.f, sti = 0.f;
    if (BIGTW) {
        float s0, c0, s1, c1;
        __sincosf((float)SIGN * twrate * (float)(n1 * u), &s0, &c0);
        __sincosf((float)SIGN * twrate * (float)(n1 << 4), &s1, &c1);
        tbr = c0; tbi = s0; str = c1; sti = s1;
    }
#pragma unroll
    for (int d = 0; d < 16; ++d) {
        float vr = yr[d], vi = yi[d];
        if (BIGTW) {
            float pr = vr * tbr - vi * tbi, pi = vr * tbi + vi * tbr;
            vr = pr; vi = pi;
            float nr = tbr * str - tbi * sti; tbi = tbr * sti + tbi * str; tbr = nr;
        }
        int k = u + (d << 4);
        if (OUT == 1) {
            rr[SWZ(k) ^ cxor] = sqrtf(fmaf(vr, vr, vi * vi)) * mscale;
        } else if (OUT == 2) {
            float mag = sqrtf(fmaf(vr, vr, vi * vi)) * mscale;
            ri[PADL + k] = mag;
            if (k >= 256 - PADL) ri[k - (256 - PADL)] = mag;
            if (k < PADR) ri[PADL + 256 + k] = mag;
        } else {
            int s = SWZ(k) ^ cxor;
            rr[s] = vr; ri[s] = vi;
        }
    }
    lds_fence();
}

template<int L, int CLOG, int RST, int SIGN, bool SWZC>
__device__ __forceinline__ void lds_dit(float* re, float* im, const float* twt, int t, int T)
{
    const float S = (float)SIGN;
    const int NC = 1 << CLOG;
    const int nbf = NC * (L >> 2);
    for (int h = 1; h < L; h <<= 2) {
        __syncthreads();
        for (int i = t; i < nbf; i += T) {
            int c = i & (NC - 1);
            int bf = i >> CLOG;
            int j = bf & (h - 1);
            int q0 = ((bf - j) << 2) + j;
            int r0 = q0, r1 = q0 + h, r2 = q0 + 2 * h, r3 = q0 + 3 * h;
            int a0, a1, a2, a3;
            if (SWZC) {
                a0 = r0 * RST + SWZI(c, r0); a1 = r1 * RST + SWZI(c, r1);
                a2 = r2 * RST + SWZI(c, r2); a3 = r3 * RST + SWZI(c, r3);
            } else {
                a0 = r0 * RST + c; a1 = r1 * RST + c; a2 = r2 * RST + c; a3 = r3 * RST + c;
            }
            float x0r = re[a0], x0i = im[a0];
            float x1r = re[a1], x1i = im[a1];
            float x2r = re[a2], x2i = im[a2];
            float x3r = re[a3], x3i = im[a3];
            if (h > 1) {
                const float* e = twt + 6 * (j * (16 / h));
                float cj = e[0], sj = S * e[1];
                float c2 = e[2], s2 = S * e[3];
                float c3 = e[4], s3 = S * e[5];
                float r;
                r = x1r * cj - x1i * sj; x1i = x1r * sj + x1i * cj; x1r = r;
                r = x2r * c2 - x2i * s2; x2i = x2r * s2 + x2i * c2; x2r = r;
                r = x3r * c3 - x3i * s3; x3i = x3r * s3 + x3i * c3; x3r = r;
            }
            float t0r = x0r + x2r, t0i = x0i + x2i;
            float t1r = x0r - x2r, t1i = x0i - x2i;
            float t2r = x1r + x3r, t2i = x1i + x3i;
            float t3r = -S * (x1i - x3i), t3i = S * (x1r - x3r);
            re[a0] = t0r + t2r; im[a0] = t0i + t2i;
            re[a1] = t1r + t3r; im[a1] = t1i + t3i;
            re[a2] = t0r - t2r; im[a2] = t0i - t2i;
            re[a3] = t1r - t3r; im[a3] = t1i - t3i;
        }
    }
    __syncthreads();
}

template<int L, int CLOG, int RST, int SIGN, bool SWZC>
__device__ __forceinline__ void lds_dif(float* re, float* im, const float* twt, int t, int T)
{
    const float S = (float)SIGN;
    const int NC = 1 << CLOG;
    const int nbf = NC * (L >> 2);
    for (int h = L >> 2; h >= 1; h >>= 2) {
        __syncthreads();
        for (int i = t; i < nbf; i += T) {
            int c = i & (NC - 1);
            int bf = i >> CLOG;
            int j = bf & (h - 1);
            int q0 = ((bf - j) << 2) + j;
            int r0 = q0, r1 = q0 + h, r2 = q0 + 2 * h, r3 = q0 + 3 * h;
            int a0, a1, a2, a3;
            if (SWZC) {
                a0 = r0 * RST + SWZI(c, r0); a1 = r1 * RST + SWZI(c, r1);
                a2 = r2 * RST + SWZI(c, r2); a3 = r3 * RST + SWZI(c, r3);
            } else {
                a0 = r0 * RST + c; a1 = r1 * RST + c; a2 = r2 * RST + c; a3 = r3 * RST + c;
            }
            float x0r = re[a0], x0i = im[a0];
            float x1r = re[a1], x1i = im[a1];
            float x2r = re[a2], x2i = im[a2];
            float x3r = re[a3], x3i = im[a3];
            float t0r = x0r + x2r, t0i = x0i + x2i;
            float t1r = x0r - x2r, t1i = x0i - x2i;
            float t2r = x1r + x3r, t2i = x1i + x3i;
            float t3r = -S * (x1i - x3i), t3i = S * (x1r - x3r);
            float y1r = t1r + t3r, y1i = t1i + t3i;
            float y2r = t0r - t2r, y2i = t0i - t2i;
            float y3r = t1r - t3r, y3i = t1i - t3i;
            re[a0] = t0r + t2r; im[a0] = t0i + t2i;
            if (h > 1) {
                const float* e = twt + 6 * (j * (16 / h));
                float cj = e[0], sj = S * e[1];
                float c2 = e[2], s2 = S * e[3];
                float c3 = e[4], s3 = S * e[5];
                re[a1] = y1r * cj - y1i * sj; im[a1] = y1r * sj + y1i * cj;
                re[a2] = y2r * c2 - y2i * s2; im[a2] = y2r * s2 + y2i * c2;
                re[a3] = y3r * c3 - y3i * s3; im[a3] = y3r * s3 + y3i * c3;
            } else {
                re[a1] = y1r; im[a1] = y1i;
                re[a2] = y2r; im[a2] = y2i;
                re[a3] = y3r; im[a3] = y3i;
            }
        }
    }
    __syncthreads();
}

// ================= XF chain =================
__global__ __launch_bounds__(256)
void xf_stage1(const float* __restrict__ x, float2* __restrict__ D)
{
    __shared__ float sre[16 * RSTR];
    __shared__ float sim[16 * RSTR];
    const int t = threadIdx.x;
    const int r = blockIdx.x >> 4;
    const int n10 = (blockIdx.x & 15) << 4;
#pragma unroll
    for (int it = 0; it < 16; ++it) {
        int flat = it * 256 + t;
        int i = flat & 15, n2 = flat >> 4;
        int n = (n10 + i) + (n2 << 8);
        sre[i * RSTR + SWZI(n2, i)] = x[(size_t)r * NN + n];
        sim[i * RSTR + SWZI(n2, i)] = 0.f;
    }
    __syncthreads();
    const int g = t >> 4, u = t & 15;
    fft256_soa<-1, true, 0, false, 0, 0>(sre + g * RSTR, sim + g * RSTR, u, n10 + g,
                                         TWO_PI / (float)NN, 1.f, g & 12, 15);
    __syncthreads();
#pragma unroll
    for (int it = 0; it < 16; ++it) {
        int flat = it * 256 + t;
        int i = flat & 15, k2 = flat >> 4;
        int s = i * RSTR + SWZI(k2, i);
        D[(size_t)r * NN + (k2 << 8) + (n10 + i)] = make_float2(sre[s], sim[s]);
    }
}

__global__ __launch_bounds__(256)
void xf_stage2(const float2* __restrict__ D, float2* __restrict__ XF)
{
    __shared__ float sre[16 * RSTR];
    __shared__ float sim[16 * RSTR];
    const int t = threadIdx.x;
    const int r = blockIdx.x >> 4;
    const int k20 = (blockIdx.x & 15) << 4;
#pragma unroll
    for (int it = 0; it < 16; ++it) {
        float2 v = D[(size_t)r * NN + ((size_t)(k20 + it) << 8) + t];
        sre[it * RSTR + SWZI(t, it)] = v.x;
        sim[it * RSTR + SWZI(t, it)] = v.y;
    }
    __syncthreads();
    const int g = t >> 4, u = t & 15;
    fft256_soa<-1, false, 0, false, 0, 0>(sre + g * RSTR, sim + g * RSTR, u, 0, 0.f, 1.f, g & 12, 15);
    __syncthreads();
#pragma unroll
    for (int it = 0; it < 16; ++it) {
        int flat = it * 256 + t;
        int fi = flat & 15, k1 = flat >> 4;
        int s = fi * RSTR + SWZI(k1, fi);
        XF[(size_t)r * NN + (size_t)(k20 + fi) + ((size_t)k1 << 8)] = make_float2(sre[s], sim[s]);
    }
}

// ================= device bodies (shared-mem carved from sm) =================
__device__ void d_fo_stage1(float* sm, int t, int blk, const float2* __restrict__ XF,
                            __half2* __restrict__ Dh)
{
    float* sre = sm; float* sim = sm + 4224;
    const int r = blk >> 4;
    const int n10 = (blk & 15) << 4;
    const int q = r;
    const int j1 = q >> 6, ql = q & 63;
    const int srow = ql >> 3, w = ql & 7;
    const int lam = j1 * 8 + w;
    const float xi = 0.35f * exp2f(-(float)lam * 0.125f);
    const float invsig = 8.0f / xi;
    const float kc = xi * (float)NN;
    const float Hh = 5.0f * (xi * 0.125f) * (float)NN;
    const int klo = (int)(kc - Hh), khi = (int)(kc + Hh) + 1;
    const int qm = (khi >= NN) ? 15 : quarter_mask(klo, khi);
#pragma unroll
    for (int it = 0; it < 16; ++it) {
        int i = t & 15, n2 = (it << 4) + (t >> 4);
        if (!(qm & (1 << (it >> 2)))) {
            sre[i * RSTR + SWZI(n2, i)] = 0.f;
            sim[i * RSTR + SWZI(n2, i)] = 0.f;
            continue;
        }
        int n = (n10 + i) + (n2 << 8);
        float nsf = (float)((n < NN / 2) ? n : n - NN);
        float vr = 0.f, vi = 0.f;
        if (fabsf(nsf - kc) <= Hh) {
            float2 v = XF[(size_t)srow * NN + n];
            float a = (nsf * (1.0f / (float)NN) - xi) * invsig;
            float wg = __expf(-0.5f * a * a) * 0.0625f;
            vr = v.x * wg; vi = v.y * wg;
        }
        sre[i * RSTR + SWZI(n2, i)] = vr;
        sim[i * RSTR + SWZI(n2, i)] = vi;
    }
    __syncthreads();
    const int g = t >> 4, u = t & 15;
    fft256_soa<1, true, 0, false, 0, 0>(sre + g * RSTR, sim + g * RSTR, u, n10 + g,
                                        TWO_PI / (float)NN, 1.f, g & 12, qm);
    __syncthreads();
#pragma unroll
    for (int it = 0; it < 16; ++it) {
        int flat = it * 256 + t;
        int i = flat & 15, k2 = flat >> 4;
        int s = i * RSTR + SWZI(k2, i);
        Dh[(size_t)r * NN + (k2 << 8) + (n10 + i)] = __floats2half2_rn(sre[s], sim[s]);
    }
}

__device__ void d_fo_mid(float* sm, int t, int blk, const __half2* __restrict__ Dh,
                         __half2* __restrict__ D2h)
{
    float* sre = sm; float* sim = sm + 4224;
    const int r = blk >> 4;
    const int k20 = (blk & 15) << 4;
#pragma unroll
    for (int it = 0; it < 16; ++it) {
        float2 v = __half22float2(Dh[(size_t)r * NN + ((size_t)(k20 + it) << 8) + t]);
        sre[it * RSTR + SWZI(t, it)] = v.x;
        sim[it * RSTR + SWZI(t, it)] = v.y;
    }
    __syncthreads();
    const int g = t >> 4, u = t & 15;
    float* rr = sre + g * RSTR; float* ri = sim + g * RSTR;
    fft256_soa<1, false, 1, false, 0, 0>(rr, ri, u, 0, 0.f, 16.0f / (float)NN, g & 12, 15);
    fft256_soa<-1, true, 0, true, 0, 0>(rr, ri, u, k20 + g, TWO_PI / (float)NN, 1.f, g & 12, 15);
    __syncthreads();
#pragma unroll
    for (int it = 0; it < 16; ++it) {
        int flat = it * 256 + t;
        int i = flat & 15, k2 = flat >> 4;
        int s = i * RSTR + SWZI(k2, i);
        D2h[(size_t)r * NN + (k2 << 8) + (k20 + i)] = __floats2half2_rn(sre[s], sim[s]);
    }
}

__device__ void d_fo_stage2(float* sm, int t, int blk, const __half2* __restrict__ D2h,
                            __half2* __restrict__ Cw)
{
    float* sre = sm; float* sim = sm + 4224;
    const int r = blk >> 4;
    const int k20 = (blk & 15) << 4;
    const int j1 = r >> 6, ql = r & 63;
#pragma unroll
    for (int it = 0; it < 16; ++it) {
        float2 v = __half22float2(D2h[(size_t)r * NN + ((size_t)(k20 + it) << 8) + t]);
        sre[it * RSTR + SWZI(t, it)] = v.x;
        sim[it * RSTR + SWZI(t, it)] = v.y;
    }
    __syncthreads();
    const int g = t >> 4, u = t & 15;
    fft256_soa<-1, false, 0, false, 0, 0>(sre + g * RSTR, sim + g * RSTR, u, 0, 0.f, 1.f, g & 12, 15);
    __syncthreads();
    const size_t base = COFF[j1] + (size_t)ql * CWW[j1];
    const int lo = CLO[j1], Wd = CWW[j1];
#pragma unroll
    for (int it = 0; it < 16; ++it) {
        int flat = it * 256 + t;
        int fi = flat & 15, k1 = flat >> 4;
        int k = (k20 + fi) + (k1 << 8);
        int ksg = (k < NN / 2) ? k : k - NN;
        int idx = ksg - lo;
        if (idx >= 0 && idx < Wd) {
            int s = fi * RSTR + SWZI(k1, fi);
            Cw[base + idx] = __floats2half2_rn(sre[s], sim[s]);
        }
    }
}

__device__ void d_sfold(float* sm, int t, int blk, const float2* __restrict__ XF,
                        const __half2* __restrict__ Cw, float* __restrict__ out)
{
    float* Gr = sm; float* Gi = sm + 256;
    const float invsigphi = 731.428571f;
    float ar = 0.f, ai = 0.f;
    if (blk < 8) {
#pragma unroll
        for (int qq = -4; qq <= 4; ++qq) {
            int ks = t + (qq << 8);
            int k = ks & (NN - 1);
            float a = ((float)ks * (1.0f / (float)NN)) * invsigphi;
            float wg = __expf(-0.5f * a * a);
            float2 v = XF[(size_t)blk * NN + k];
            ar = fmaf(v.x, wg, ar); ai = fmaf(v.y, wg, ai);
        }
    } else {
        int q = blk - 8;
        int j1 = q >> 6, ql = q & 63;
        size_t base = COFF[j1] + (size_t)ql * CWW[j1];
        int lo = CLO[j1], Wd = CWW[j1], ring = CRING[j1];
#pragma unroll
        for (int qq = -4; qq <= 4; ++qq) {
            int ks = t + (qq << 8);
            float a = ((float)ks * (1.0f / (float)NN)) * invsigphi;
            float wg = __expf(-0.5f * a * a);
            int idx = ring ? ((ks - lo) & (Wd - 1)) : (ks - lo);
            float2 v = __half22float2(Cw[base + idx]);
            ar = fmaf(v.x, wg, ar); ai = fmaf(v.y, wg, ai);
        }
    }
    Gr[t] = ar; Gi[t] = ai;
    __syncthreads();
    float sb, cb;
    __sincosf((TWO_PI / 256.0f) * (float)t, &sb, &cb);
    float wr = 1.f, wi = 0.f, s = 0.f;
    for (int kk = 0; kk < 256; ++kk) {
        s = fmaf(Gr[kk], wr, s);
        s = fmaf(-Gi[kk], wi, s);
        float nr = wr * cb - wi * sb; wi = wr * sb + wi * cb; wr = nr;
    }
    s *= (1.0f / (float)NN);
    float mag = sqrtf(fmaf(s, s, 1e-8f));
    float val = logf(mag + 1e-8f);
    int b, chan;
    if (blk < 8) { b = blk; chan = 0; }
    else { int q = blk - 8; int j1 = q >> 6, ql = q & 63; b = ql >> 3; chan = 1 + j1 * 8 + (ql & 7); }
    out[((size_t)b * 289 + chan) * 256 + t] = val;
}

__device__ __forceinline__ void so_decode_full(int q, int& j1, int& j2, int& rb)
{
    int pp = q >> 6;
    rb = q & 63;
    j2 = (pp == 0) ? 1 : 2;
    j1 = (pp == 0) ? 0 : pp - 1;
}
__device__ __forceinline__ void so_decode_dec16(int q, int& j1, int& j2, int& rb)
{
    int pp = q >> 6;
    rb = q & 63;
    j2 = (pp < 3) ? 3 : 4;
    j1 = (pp < 3) ? pp : pp - 3;
}

__device__ void d_so_stage1(float* sm, int t, int blk, const __half2* __restrict__ Cw,
                            __half2* __restrict__ Dh)
{
    float* sre = sm; float* sim = sm + 4224;
    const int r = blk >> 4;
    const int n10 = (blk & 15) << 4;
    int j1, j2, rb;
    so_decode_full(r, j1, j2, rb);
    const float xi2 = 0.35f * exp2f(-(float)j2);
    const float invsig = 1.0f / (0.6f * xi2);
    const float kc = xi2 * (float)NN;
    const float Hh = 5.0f * (0.6f * xi2) * (float)NN;
    const int klo = (int)(kc - Hh), khi = (int)(kc + Hh) + 1;
    const int qm = (klo >= 0 && khi >= NN) ? 15 : quarter_mask(klo, khi);
    const size_t base = COFF[j1] + (size_t)rb * CWW[j1];
    const int lo = CLO[j1], Wd = CWW[j1];
#pragma unroll
    for (int it = 0; it < 16; ++it) {
        int i = t & 15, n2 = (it << 4) + (t >> 4);
        if (!(qm & (1 << (it >> 2)))) {
            sre[i * RSTR + SWZI(n2, i)] = 0.f;
            sim[i * RSTR + SWZI(n2, i)] = 0.f;
            continue;
        }
        int n = (n10 + i) + (n2 << 8);
        int ksg = (n < NN / 2) ? n : n - NN;
        float nsf = (float)ksg;
        float vr = 0.f, vi = 0.f;
        int idx = ksg - lo;
        if (fabsf(nsf - kc) <= Hh && idx >= 0 && idx < Wd) {
            float2 v = __half22float2(Cw[base + idx]);
            float a = (nsf * (1.0f / (float)NN) - xi2) * invsig;
            float wg = __expf(-0.5f * a * a) * (1.0f / 256.0f);
            vr = v.x * wg; vi = v.y * wg;
        }
        sre[i * RSTR + SWZI(n2, i)] = vr;
        sim[i * RSTR + SWZI(n2, i)] = vi;
    }
    __syncthreads();
    const int g = t >> 4, u = t & 15;
    fft256_soa<1, true, 0, false, 0, 0>(sre + g * RSTR, sim + g * RSTR, u, n10 + g,
                                        TWO_PI / (float)NN, 1.f, g & 12, qm);
    __syncthreads();
#pragma unroll
    for (int it = 0; it < 16; ++it) {
        int flat = it * 256 + t;
        int i = flat & 15, k2 = flat >> 4;
        int s = i * RSTR + SWZI(k2, i);
        Dh[(size_t)r * NN + (k2 << 8) + (n10 + i)] = __floats2half2_rn(sre[s], sim[s]);
    }
}

__device__ void d_so_stage2(float* sm, int t, int blk, const __half2* __restrict__ Dh,
                            float* __restrict__ S2acc)
{
    float* sre = sm; float* sim = sm + 4224;
    float* wtab = sm + 8448;   // [16][8]
    const int r = blk >> 4;
    const int k20 = (blk & 15) << 4;
#pragma unroll
    for (int it = 0; it < 16; ++it) {
        float2 v = __half22float2(Dh[(size_t)r * NN + ((size_t)(k20 + it) << 8) + t]);
        sre[it * RSTR + SWZI(t, it)] = v.x;
        sim[it * RSTR + SWZI(t, it)] = v.y;
    }
    if (t < 128) {
        int fi = t >> 3, dd = (t & 7) - 4;
        int w = k20 + fi + (dd << 8) + 768;
        float val = 0.f;
        if (w >= 0 && w <= 1536) {
            float m = (float)(w - 768);
            val = 0.003426963f * __expf(-3.690276e-5f * m * m);
        }
        wtab[fi * 8 + (t & 7)] = val;
    }
    __syncthreads();
    const int g = t >> 4, u = t & 15;
    fft256_soa<1, false, 2, false, 4, 3>(sre + g * RSTR, sim + g * RSTR, u, 0, 0.f, 1.f, g & 12, 15);
    __syncthreads();
    float acc = 0.f;
#pragma unroll
    for (int fi = 0; fi < 16; ++fi) {
        const float* row = sim + fi * RSTR;
#pragma unroll
        for (int dd = 0; dd < 8; ++dd)
            acc = fmaf(row[t + dd], wtab[fi * 8 + dd], acc);
    }
    atomicAdd(&S2acc[(size_t)r * 256 + t], acc * (1.0f / 256.0f));
}

template<int MODE>
__device__ void d_dec16_s1(float* sm, int t, int blk, const float2* __restrict__ XF,
                           const __half2* __restrict__ Cw, __half2* __restrict__ Dh16)
{
    float* sre = sm; float* sim = sm + 4096; float* twt = sm + 8192;
    const int r = blk >> 2;
    const int c0 = (blk & 3) << 6;
    const int q = r;
    float xi, invsig, kc, Hh; int srow = 0; size_t cbase = 0; int lo = 0, Wd = 0, ring = 0;
    if (MODE == 1) {
        int j1 = 2 + (q >> 6); int ql = q & 63; srow = ql >> 3;
        int lam = j1 * 8 + (ql & 7);
        xi = 0.35f * exp2f(-(float)lam * 0.125f);
        invsig = 8.0f / xi; kc = xi * (float)NN; Hh = 6.10f * (xi * 0.125f) * (float)NN;
    } else {
        int j1, j2, rb;
        so_decode_dec16(q, j1, j2, rb);
        xi = 0.35f * exp2f(-(float)j2);
        invsig = 1.0f / (0.6f * xi); kc = xi * (float)NN;
        Hh = fminf(6.10f * (0.6f * xi) * (float)NN, 7967.0f);
        cbase = COFF[j1] + (size_t)rb * CWW[j1]; lo = CLO[j1]; Wd = CWW[j1]; ring = CRING[j1];
    }
    build_tw6(twt, t);
    const int klo = (int)ceilf(kc - Hh);
#pragma unroll
    for (int it = 0; it < 16; ++it) {
        int flat = it * 256 + t;
        int c = flat & 63, n2 = flat >> 6;
        int kap = (c0 + c) + (n2 << 8);
        int kk = klo + (int)(((unsigned)(kap - klo)) & 16383u);
        float vr = 0.f, vi = 0.f;
        if (fabsf((float)kk - kc) <= Hh) {
            float2 v;
            bool ok = true;
            if (MODE == 1) v = XF[(size_t)srow * NN + (kk & (NN - 1))];
            else {
                int idx;
                if (ring) idx = (kk - lo) & (Wd - 1);
                else { idx = kk - lo; ok = (idx >= 0 && idx < Wd); }
                v = ok ? __half22float2(Cw[cbase + idx]) : make_float2(0.f, 0.f);
            }
            float a = ((float)kk * (1.0f / (float)NN) - xi) * invsig;
            float wg = __expf(-0.5f * a * a) * 0.015625f;
            vr = v.x * wg; vi = v.y * wg;
        }
        int p = rev64(n2);
        sre[(p << 6) + c] = vr;
        sim[(p << 6) + c] = vi;
    }
    lds_dit<64, 6, 64, 1, false>(sre, sim, twt, t, 256);
    {
        const int c = t & 63, r0 = t >> 6;
        float sA, cA, sD, cD;
        __sincosf((TWO_PI / 16384.0f) * (float)(r0 * (c0 + c)), &sA, &cA);
        __sincosf((TWO_PI / 16384.0f) * (float)(4 * (c0 + c)), &sD, &cD);
#pragma unroll
        for (int it = 0; it < 16; ++it) {
            int row = (it << 2) + r0;
            int a = (row << 6) + c;
            float rr = sre[a] * cA - sim[a] * sA;
            sim[a] = sre[a] * sA + sim[a] * cA; sre[a] = rr;
            float nc = cA * cD - sA * sD; sA = cA * sD + sA * cD; cA = nc;
        }
    }
    __syncthreads();
#pragma unroll
    for (int it = 0; it < 16; ++it) {
        int flat = it * 256 + t;
        int c = flat & 63, row = flat >> 6;
        Dh16[(size_t)r * 16384 + (row << 8) + (c0 + c)] =
            __floats2half2_rn(sre[(row << 6) + c], sim[(row << 6) + c]);
    }
}

__device__ void d_dec16_s2so(float* sm, int t, int blk, const __half2* __restrict__ Dh16,
                             float* __restrict__ S2acc)
{
    float* sre = sm; float* sim = sm + 4224;
    float* wtab = sm + 8448;   // [16][6]
    const int r = blk >> 2;
    const int k2base = (blk & 3) << 4;
#pragma unroll
    for (int it = 0; it < 16; ++it) {
        float2 v = __half22float2(Dh16[(size_t)r * 16384 + ((k2base + it) << 8) + t]);
        sre[it * RSTR + SWZI(t, it)] = v.x;
        sim[it * RSTR + SWZI(t, it)] = v.y;
    }
    if (t < 96) {
        int p = t / 6, dl = t % 6;
        float w = (float)(256 * (dl - 2) - 4 * (k2base + p));
        wtab[p * 6 + dl] = 0.003426963f * __expf(-3.690276e-5f * w * w);
    }
    __syncthreads();
    const int g = t >> 4, u = t & 15;
    fft256_soa<1, false, 2, false, 3, 2>(sre + g * RSTR, sim + g * RSTR, u, 0, 0.f,
                                         64.0f / (float)NN, g & 12, 15);
    __syncthreads();
    float acc = 0.f;
#pragma unroll
    for (int p = 0; p < 16; ++p) {
        const float* row = sim + p * RSTR;
#pragma unroll
        for (int dl = 0; dl < 6; ++dl)
            acc = fmaf(row[t + 5 - dl], wtab[p * 6 + dl], acc);
    }
    atomicAdd(&S2acc[(size_t)(192 + r) * 256 + t], acc * 4.0f);
}

__device__ void d_dec16_s2fo(float* sm, int t, int blk, const __half2* __restrict__ Dh16,
                             __half2* __restrict__ D2h16)
{
    float* sre = sm; float* sim = sm + 4224;
    const int r = blk >> 2;
    const int k2base = (blk & 3) << 4;
#pragma unroll
    for (int it = 0; it < 16; ++it) {
        float2 v = __half22float2(Dh16[(size_t)r * 16384 + ((k2base + it) << 8) + t]);
        sre[it * RSTR + SWZI(t, it)] = v.x;
        sim[it * RSTR + SWZI(t, it)] = v.y;
    }
    __syncthreads();
    const int g = t >> 4, u = t & 15;
    float* rr = sre + g * RSTR; float* ri = sim + g * RSTR;
    fft256_soa<1, false, 1, false, 0, 0>(rr, ri, u, 0, 0.f, 256.0f / (float)NN, g & 12, 15);
    fft256_soa<-1, true, 0, true, 0, 0>(rr, ri, u, k2base + g, TWO_PI / 16384.0f, 1.f, g & 12, 15);
    __syncthreads();
#pragma unroll
    for (int it = 0; it < 16; ++it) {
        int a = it * RSTR + SWZI(t, it);
        D2h16[(size_t)r * 16384 + ((k2base + it) << 8) + t] = __floats2half2_rn(sre[a], sim[a]);
    }
}

__device__ void d_dec16_s3fo(float* sm, int t, int blk, const __half2* __restrict__ D2h16,
                             __half2* __restrict__ Cw)
{
    float* sre = sm; float* sim = sm + 4096; float* twt = sm + 8192;
    const int r = blk >> 2;
    const int c0 = (blk & 3) << 6;
    const int j1 = 2 + (r >> 6), ql = r & 63;
    build_tw6(twt, t);
#pragma unroll
    for (int it = 0; it < 16; ++it) {
        int flat = it * 256 + t;
        int c = flat & 63, m2 = flat >> 6;
        float2 v = __half22float2(D2h16[(size_t)r * 16384 + (m2 << 8) + (c0 + c)]);
        sre[(m2 << 6) + c] = v.x;
        sim[(m2 << 6) + c] = v.y;
    }
    lds_dif<64, 6, 64, -1, false>(sre, sim, twt, t, 256);
    const int lo = CLO[j1];
    const size_t rbase = COFF[j1] + (size_t)ql * 16384;
#pragma unroll
    for (int it = 0; it < 16; ++it) {
        int flat = it * 256 + t;
        int c = flat & 63, p = flat >> 6;
        int kap = (c0 + c) + (rev64(p) << 8);
        int ks = (kap < 8192) ? kap : kap - 16384;
        int idx = (ks - lo) & 16383;
        int a = (p << 6) + c;
        Cw[rbase + idx] = __floats2half2_rn(sre[a], sim[a]);
    }
}

__device__ void d_m4k_fo(float* sm, int t, int blk, const float2* __restrict__ XF,
                         __half2* __restrict__ Cw)
{
    float* sre = sm; float* sim = sm + 4224; float* twt = sm + 8448;
    const int q = blk;
    const int j1 = 5 + (q >> 6), ql = q & 63;
    const int srow = ql >> 3;
    const int lam = j1 * 8 + (ql & 7);
    const float xi = 0.35f * exp2f(-(float)lam * 0.125f);
    const float invsig = 8.0f / xi;
    const float kc = xi * (float)NN;
    const float Hh = 6.10f * (xi * 0.125f) * (float)NN;
    const int klo = (int)ceilf(kc - Hh);
    build_tw6(twt, t);
#pragma unroll
    for (int it = 0; it < 16; ++it) {
        int kap = t + (it << 8);
        int kk = klo + (int)(((unsigned)(kap - klo)) & 4095u);
        float vr = 0.f, vi = 0.f;
        if (fabsf((float)kk - kc) <= Hh) {
            float2 v = XF[(size_t)srow * NN + (kk & (NN - 1))];
            float a = ((float)kk * (1.0f / (float)NN) - xi) * invsig;
            float wg = __expf(-0.5f * a * a);
            vr = v.x * wg; vi = v.y * wg;
        }
        int p = rev16(it);
        sre[p * RSTR + SWZI(t, p)] = vr;
        sim[p * RSTR + SWZI(t, p)] = vi;
    }
    lds_dit<16, 8, RSTR, 1, true>(sre, sim, twt, t, 256);
    {
        float sD, cD; __sincosf((TWO_PI / 4096.0f) * (float)t, &sD, &cD);
        float cA = 1.f, sA = 0.f;
#pragma unroll
        for (int it = 0; it < 16; ++it) {
            int a = it * RSTR + SWZI(t, it);
            float rr = sre[a] * cA - sim[a] * sA;
            sim[a] = sre[a] * sA + sim[a] * cA; sre[a] = rr;
            float nc = cA * cD - sA * sD; sA = cA * sD + sA * cD; cA = nc;
        }
    }
    __syncthreads();
    const int g = t >> 4, u = t & 15;
    float* rr = sre + g * RSTR; float* ri = sim + g * RSTR;
    fft256_soa<1, false, 1, false, 0, 0>(rr, ri, u, 0, 0.f, 16.0f / (float)NN, g & 12, 15);
    fft256_soa<-1, true, 0, true, 0, 0>(rr, ri, u, g, TWO_PI / 4096.0f, 1.f, g & 12, 15);
    lds_dif<16, 8, RSTR, -1, true>(sre, sim, twt, t, 256);
    const int lo = CLO[j1];
    const size_t rbase = COFF[j1] + (size_t)ql * 4096;
#pragma unroll
    for (int it = 0; it < 16; ++it) {
        int kap = t + (rev16(it) << 8);
        int ks = (kap < 2048) ? kap : kap - 4096;
        int idx = (ks - lo) & 4095;
        int a = it * RSTR + SWZI(t, it);
        Cw[rbase + idx] = __floats2half2_rn(sre[a], sim[a]);
    }
}

__device__ void d_m4k_so(float* sm, int t, int blk, const __half2* __restrict__ Cw,
                         float* __restrict__ out)
{
    float* sre = sm; float* sim = sm + 4224;
    float* twt = sm + 8448; float* wtab = sm + 8544;   // [16][6]
    const int q = blk;
    const int pp = q >> 6, rb = q & 63;
    int j1, j2;
    if (pp < 5)       { j2 = 5; j1 = pp; }
    else if (pp < 11) { j2 = 6; j1 = pp - 5; }
    else              { j2 = 7; j1 = pp - 11; }
    const float xi2 = 0.35f * exp2f(-(float)j2);
    const float invsig = 1.0f / (0.6f * xi2);
    const float kc = xi2 * (float)NN;
    const float Hh = fminf(6.10f * (0.6f * xi2) * (float)NN, 1823.0f);
    const int klo = (int)ceilf(kc - Hh);
    const size_t cbase = COFF[j1] + (size_t)rb * CWW[j1];
    const int lo = CLO[j1], Wd = CWW[j1], ring = CRING[j1];
    build_tw6(twt, t);
#pragma unroll
    for (int it = 0; it < 16; ++it) {
        int kap = t + (it << 8);
        int kk = klo + (int)(((unsigned)(kap - klo)) & 4095u);
        float vr = 0.f, vi = 0.f;
        if (fabsf((float)kk - kc) <= Hh) {
            int idx; bool ok = true;
            if (ring) idx = (kk - lo) & (Wd - 1);
            else { idx = kk - lo; ok = (idx >= 0 && idx < Wd); }
            if (ok) {
                float2 v = __half22float2(Cw[cbase + idx]);
                float a = ((float)kk * (1.0f / (float)NN) - xi2) * invsig;
                float wg = __expf(-0.5f * a * a);
                vr = v.x * wg; vi = v.y * wg;
            }
        }
        int p = rev16(it);
        sre[p * RSTR + SWZI(t, p)] = vr;
        sim[p * RSTR + SWZI(t, p)] = vi;
    }
    if (t < 96) {
        int p = t / 6, dl = t % 6;
        float w = (float)(256 * (dl - 2) - 16 * p);
        wtab[p * 6 + dl] = 0.003426963f * __expf(-3.690276e-5f * w * w);
    }
    lds_dit<16, 8, RSTR, 1, true>(sre, sim, twt, t, 256);
    {
        float sD, cD; __sincosf((TWO_PI / 4096.0f) * (float)t, &sD, &cD);
        float cA = 1.f, sA = 0.f;
#pragma unroll
        for (int it = 0; it < 16; ++it) {
            int a = it * RSTR + SWZI(t, it);
            float rr = sre[a] * cA - sim[a] * sA;
            sim[a] = sre[a] * sA + sim[a] * cA; sre[a] = rr;
            float nc = cA * cD - sA * sD; sA = cA * sD + sA * cD; cA = nc;
        }
    }
    __syncthreads();
    const int g = t >> 4, u = t & 15;
    fft256_soa<1, false, 2, false, 3, 2>(sre + g * RSTR, sim + g * RSTR, u, 0, 0.f,
                                         1.0f / (float)NN, g & 12, 15);
    __syncthreads();
    float acc = 0.f;
#pragma unroll
    for (int p = 0; p < 16; ++p) {
        const float* row = sim + p * RSTR;
#pragma unroll
        for (int dl = 0; dl < 6; ++dl)
            acc = fmaf(row[t + 5 - dl], wtab[p * 6 + dl], acc);
    }
    acc *= 16.0f;
    const int b = rb >> 3;
    const int chan = 65 + 4 * j2 * (j2 - 1) + j1 * 8 + (rb & 7);
    float mag = sqrtf(fmaf(acc, acc, 1e-8f));
    out[((size_t)b * 289 + chan) * 256 + t] = logf(mag + 1e-8f);
}

// ================= dispatchers =================
__global__ __launch_bounds__(256)
void fo_s1_kernel(const float2* __restrict__ XF, __half2* __restrict__ Cw,
                  __half2* __restrict__ DhB, __half2* __restrict__ Dh16)
{
    __shared__ float sm[8704];
    const int t = threadIdx.x;
    const int b = blockIdx.x;
    if (b < 192) d_m4k_fo(sm, t, b, XF, Cw);
    else if (b < 960) d_dec16_s1<1>(sm, t, b - 192, XF, nullptr, Dh16);
    else d_fo_stage1(sm, t, b - 960, XF, DhB);
}

__global__ __launch_bounds__(256)
void fo_s2_kernel(const __half2* __restrict__ DhB, const __half2* __restrict__ Dh16,
                  __half2* __restrict__ D2h, __half2* __restrict__ D2h16)
{
    __shared__ float sm[8704];
    const int t = threadIdx.x;
    const int b = blockIdx.x;
    if (b < 768) d_dec16_s2fo(sm, t, b, Dh16, D2h16);
    else d_fo_mid(sm, t, b - 768, DhB, D2h);
}

__global__ __launch_bounds__(256)
void fo_s3_kernel(const __half2* __restrict__ D2h, const __half2* __restrict__ D2h16,
                  __half2* __restrict__ Cw)
{
    __shared__ float sm[8704];
    const int t = threadIdx.x;
    const int b = blockIdx.x;
    if (b < 768) d_dec16_s3fo(sm, t, b, D2h16, Cw);
    else d_fo_stage2(sm, t, b - 768, D2h, Cw);
}

__global__ __launch_bounds__(256)
void so_1_kernel(const float2* __restrict__ XF, const __half2* __restrict__ Cw,
                 __half2* __restrict__ DhS, __half2* __restrict__ Dh16so,
                 float* __restrict__ out)
{
    __shared__ float sm[8704];
    const int t = threadIdx.x;
    const int b = blockIdx.x;
    if (b < 1152) d_m4k_so(sm, t, b, Cw, out);
    else if (b < 2944) d_dec16_s1<2>(sm, t, b - 1152, nullptr, Cw, Dh16so);
    else if (b < 6016) d_so_stage1(sm, t, b - 2944, Cw, DhS);
    else d_sfold(sm, t, b - 6016, XF, Cw, out);
}

__global__ __launch_bounds__(256)
void so_2_kernel(const __half2* __restrict__ DhS, const __half2* __restrict__ Dh16so,
                 float* __restrict__ S2acc)
{
    __shared__ float sm[8704];
    const int t = threadIdx.x;
    const int b = blockIdx.x;
    if (b < 1792) d_dec16_s2so(sm, t, b, Dh16so, S2acc);
    else d_so_stage2(sm, t, b - 1792, DhS, S2acc);
}

__global__ __launch_bounds__(256)
void s2final(const float* __restrict__ S2acc, float* __restrict__ out)
{
    const int q = blockIdx.x, n = threadIdx.x;
    int j1, j2, rb;
    if (q < 192) so_decode_full(q, j1, j2, rb);
    else         so_decode_dec16(q - 192, j1, j2, rb);
    const int b = rb >> 3;
    const int chan = 65 + 4 * j2 * (j2 - 1) + j1 * 8 + (rb & 7);
    float s = S2acc[(size_t)q * 256 + n];
    float mag = sqrtf(fmaf(s, s, 1e-8f));
    out[((size_t)b * 289 + chan) * 256 + n] = logf(mag + 1e-8f);
}

__global__ void zero2_kernel(float* a, int na, float* b, int nb)
{
    int i = blockIdx.x * 256 + threadIdx.x;
    if (i < na) a[i] = 0.f;
    else if (i < na + nb) b[i - na] = 0.f;
}

extern "C" void kernel_launch(void* const* d_in, const int* in_sizes, int n_in,
                              void* d_out, int out_size, void* d_ws, size_t ws_size,
                              hipStream_t stream)
{
    const float* x = (const float*)d_in[0];
    float* out = (float*)d_out;
    char* ws = (char*)d_ws;

    size_t off = 0;
    float2*  XF    = (float2*)ws;                 off += 8ul * NN * 8;
    __half2* Cw    = (__half2*)(ws + off);        off += CTOT * 4ul;
    float*   S2acc = (float*)(ws + off);          off += 640ul * 256 * 4;
    off = (off + 255) & ~255ul;
    char* sc = ws + off;

    // fo-phase scratch (92.3 MB)
    __half2* DhB   = (__half2*)sc;                        // 128 rows x 64K = 32 MB
    __half2* D2h   = (__half2*)(sc + 33554432ul);         // 32 MB
    __half2* Dh16  = (__half2*)(sc + 67108864ul);         // 192 x 16K = 12 MB
    __half2* D2h16 = (__half2*)(sc + 79691776ul);         // 12 MB
    // so-phase scratch reuses the same region (79.7 MB)
    __half2* DhS    = (__half2*)sc;                       // 192 rows x 64K = 48 MB
    __half2* Dh16so = (__half2*)(sc + 50331648ul);        // 448 x 16K = 28 MB
    float2*  Df     = (float2*)sc;                        // 4 MB (XF stage scratch)

    {
        int nz = 8 * 289 * 256;
        int na = 640 * 256;
        zero2_kernel<<<(nz + na + 255) / 256, 256, 0, stream>>>(out + nz, nz, S2acc, na);
    }

    // XF = fft(x)
    xf_stage1<<<8 * 16, 256, 0, stream>>>(x, Df);
    xf_stage2<<<8 * 16, 256, 0, stream>>>(Df, XF);

    // first order, all resolutions, stage-wise fused
    fo_s1_kernel<<<3008, 256, 0, stream>>>(XF, Cw, DhB, Dh16);
    fo_s2_kernel<<<2816, 256, 0, stream>>>(DhB, Dh16, D2h, D2h16);
    fo_s3_kernel<<<2816, 256, 0, stream>>>(D2h, D2h16, Cw);

    // second order + S0/S1, fused
    so_1_kernel<<<6536, 256, 0, stream>>>(XF, Cw, DhS, Dh16so, out);
    so_2_kernel<<<4864, 256, 0, stream>>>(DhS, Dh16so, S2acc);
    s2final<<<640, 256, 0, stream>>>(S2acc, out);
}